// Round 5
// baseline (24546.864 us; speedup 1.0000x reference)
//
#include <hip/hip_runtime.h>
#include <math.h>

#define SLEN 8192
#define DIM  256
#define H2N  256
#define G4   1024
#define NTAG 16
#define NEGV (-10000.0f)

// ws layout (floats unless noted)
#define OFF_PRE_F   0
#define OFF_PRE_B   (SLEN*G4)
#define OFF_HS_F    (2*SLEN*G4)
#define OFF_HS_B    (2*SLEN*G4 + SLEN*H2N)
#define OFF_FEATS   (2*SLEN*G4 + 2*SLEN*H2N)
#define WS_NEEDED   ((size_t)(OFF_FEATS + SLEN*NTAG) * 4)

// ---------------- K1: pre = gather(emb, sentence[±]) @ w_ih^T + b ----------------
__global__ __launch_bounds__(256) void gemm_pre(
    const int* __restrict__ sent, const float* __restrict__ emb,
    const float* __restrict__ wf, const float* __restrict__ bf,
    const float* __restrict__ wb, const float* __restrict__ bb,
    float* __restrict__ pre_f, float* __restrict__ pre_b)
{
    const int dir = blockIdx.z;
    const float* w    = dir ? wb : wf;
    const float* bias = dir ? bb : bf;
    float* out        = dir ? pre_b : pre_f;
    const int m0 = blockIdx.x * 64, n0 = blockIdx.y * 64;

    __shared__ float As[64][17];
    __shared__ float Bs[64][17];
    __shared__ int   sidx[64];

    const int tid = threadIdx.x;
    const int tx = tid & 15, ty = tid >> 4;

    if (tid < 64) {
        int m = m0 + tid;
        int pos = dir ? (SLEN - 1 - m) : m;
        sidx[tid] = sent[pos];
    }
    __syncthreads();

    float acc[4][4];
#pragma unroll
    for (int i = 0; i < 4; i++)
#pragma unroll
        for (int j = 0; j < 4; j++) acc[i][j] = 0.f;

    const int lr = tid >> 2, lc = (tid & 3) * 4;

    for (int k0 = 0; k0 < DIM; k0 += 16) {
        float4 av = *(const float4*)(emb + (size_t)sidx[lr] * DIM + k0 + lc);
        float4 bv = *(const float4*)(w + (size_t)(n0 + lr) * DIM + k0 + lc);
        As[lr][lc+0] = av.x; As[lr][lc+1] = av.y; As[lr][lc+2] = av.z; As[lr][lc+3] = av.w;
        Bs[lr][lc+0] = bv.x; Bs[lr][lc+1] = bv.y; Bs[lr][lc+2] = bv.z; Bs[lr][lc+3] = bv.w;
        __syncthreads();
#pragma unroll
        for (int k = 0; k < 16; k++) {
            float a[4], b[4];
#pragma unroll
            for (int i = 0; i < 4; i++) a[i] = As[ty*4+i][k];
#pragma unroll
            for (int j = 0; j < 4; j++) b[j] = Bs[tx*4+j][k];
#pragma unroll
            for (int i = 0; i < 4; i++)
#pragma unroll
                for (int j = 0; j < 4; j++) acc[i][j] += a[i] * b[j];
        }
        __syncthreads();
    }

    float4 b4 = *(const float4*)(bias + n0 + tx*4);
#pragma unroll
    for (int i = 0; i < 4; i++) {
        float4 v;
        v.x = acc[i][0] + b4.x; v.y = acc[i][1] + b4.y;
        v.z = acc[i][2] + b4.z; v.w = acc[i][3] + b4.w;
        *(float4*)(out + (size_t)(m0 + ty*4 + i) * G4 + n0 + tx*4) = v;
    }
}

__device__ __forceinline__ float fast_sigmoid(float x) {
    return 1.f / (1.f + __expf(-x));
}
__device__ __forceinline__ float fast_tanh(float x) {
    float xc = fminf(fmaxf(x, -15.f), 15.f);
    float e = __expf(2.f * xc);
    return (e - 1.f) / (e + 1.f);
}

// ---------------- K2: two LSTMs, 32 blocks/direction, W in LDS (packed) ----------------
// R4 counters: SQ_LDS_BANK_CONFLICT=1.34e8 (w_lds[32][260] -> 8-way) and
// FETCH 291 MB (4 redundant poll loads/iter). Fixes:
//  * W packed as w_pack4[j*64 + lane]: lane-stride-1 float4 reads ->
//    canonical conflict-free LDS pattern. Same values, same FMA order.
//  * Polls: one dword at a time, sequential spins -> 4x less LLC traffic.
// Sync unchanged: data-as-flag (mantissa bit0=1, <=1 ulp), agent-scope
// relaxed store/load, monotone fresh addresses (poison 0xAA has bit0=0).
__global__ __launch_bounds__(64) void lstm_kernel(
    const float* __restrict__ pre_f, const float* __restrict__ pre_b,
    const float* __restrict__ whh_f, const float* __restrict__ whh_b,
    const float* __restrict__ h0_f, const float* __restrict__ c0_f,
    const float* __restrict__ h0_b, const float* __restrict__ c0_b,
    float* __restrict__ hs_f, float* __restrict__ hs_b)
{
    const int blk = blockIdx.x;            // 0..63
    const int d = blk >> 5, cb = blk & 31; // direction, cell-block
    const int cell0 = cb * 8;
    const float* pre = d ? pre_b : pre_f;
    const float* whh = d ? whh_b : whh_f;
    const float* h0  = d ? h0_b : h0_f;
    const float* c0  = d ? c0_b : c0_f;
    float* hs        = d ? hs_b : hs_f;

    const int l = threadIdx.x;       // 0..63
    const int r = l >> 1;            // local row 0..31 (gate-major)
    const int half = l & 1;          // k-half: [half*128, half*128+128)
    const int g = r >> 3, cl = r & 7;
    const int grow = g * 256 + cell0 + cl;   // global gate row (0..1023)

    __shared__ __align__(16) float4 w_pack4[32 * 64];   // 32 KB, [j][lane]
    __shared__ __align__(16) float  h_lds[256];

    // one-time weight stage into packed layout: lane l writes [j*64+l]
    {
        const float4* src = (const float4*)(whh + (size_t)grow * H2N + half * 128);
#pragma unroll
        for (int j = 0; j < 32; j++) w_pack4[j * 64 + l] = src[j];
    }
    ((float4*)h_lds)[l] = ((const float4*)h0)[l];
    float c = (l < 8) ? c0[cell0 + l] : 0.f;
    __syncthreads();

    const float* pre_base = pre + grow;
    float pre_cur = (half == 0) ? pre_base[0] : 0.f;
    const int ai = l & 7;            // activation cell index (lanes 0..7)

    for (int t = 0; t < SLEN; t++) {
        float pre_next = (half == 0 && t < SLEN - 1) ? pre_base[(size_t)(t + 1) * G4] : 0.f;

        // dot over this thread's k-half
        float a0 = pre_cur, a1 = 0.f, a2 = 0.f, a3 = 0.f;
        const float4* hrow4 = (const float4*)(h_lds + half * 128);
#pragma unroll
        for (int j = 0; j < 32; j++) {
            float4 wv = w_pack4[j * 64 + l];
            float4 hv = hrow4[j];
            a0 += wv.x * hv.x; a1 += wv.y * hv.y;
            a2 += wv.z * hv.z; a3 += wv.w * hv.w;
        }
        float sum = (a0 + a1) + (a2 + a3);
        sum += __shfl_xor(sum, 1, 64);   // row r total at lanes 2r, 2r+1

        // gate sums for cell ai: rows ai, 8+ai, 16+ai, 24+ai
        float s_i = __shfl(sum, 2 * ai, 64);
        float s_f = __shfl(sum, 16 + 2 * ai, 64);
        float s_g = __shfl(sum, 32 + 2 * ai, 64);
        float s_o = __shfl(sum, 48 + 2 * ai, 64);

        if (l < 8) {
            float i_ = fast_sigmoid(s_i);
            float f_ = fast_sigmoid(s_f);
            float g_ = fast_tanh(s_g);
            float o_ = fast_sigmoid(s_o);
            c = f_ * c + i_ * g_;
            float h = o_ * fast_tanh(c);
            unsigned hm = __float_as_uint(h) | 1u;   // flag bit, <=1 ulp
            __hip_atomic_store((unsigned*)hs + (size_t)t * H2N + cell0 + l, hm,
                               __ATOMIC_RELAXED, __HIP_MEMORY_SCOPE_AGENT);
        }

        // every lane pulls 4 cells; sequential per-dword spins (1 load/iter)
        const unsigned* hsrc = (const unsigned*)hs + (size_t)t * H2N + 4 * l;
        float4 hv4;
        {
            unsigned v; int spin = 0;
            do { v = __hip_atomic_load(hsrc + 0, __ATOMIC_RELAXED, __HIP_MEMORY_SCOPE_AGENT); }
            while (!(v & 1u) && ++spin < 3000000);
            hv4.x = __uint_as_float(v);
            spin = 0;
            do { v = __hip_atomic_load(hsrc + 1, __ATOMIC_RELAXED, __HIP_MEMORY_SCOPE_AGENT); }
            while (!(v & 1u) && ++spin < 3000000);
            hv4.y = __uint_as_float(v);
            spin = 0;
            do { v = __hip_atomic_load(hsrc + 2, __ATOMIC_RELAXED, __HIP_MEMORY_SCOPE_AGENT); }
            while (!(v & 1u) && ++spin < 3000000);
            hv4.z = __uint_as_float(v);
            spin = 0;
            do { v = __hip_atomic_load(hsrc + 3, __ATOMIC_RELAXED, __HIP_MEMORY_SCOPE_AGENT); }
            while (!(v & 1u) && ++spin < 3000000);
            hv4.w = __uint_as_float(v);
        }
        *(float4*)(h_lds + 4 * l) = hv4;
        __syncthreads();             // single wave: lgkm drain + barrier
        pre_cur = pre_next;
    }
}

// ---------------- K3: feats = concat(hs_f[s], hs_b[S-1-s]) @ w_out^T + b_out ----------------
__global__ __launch_bounds__(256) void feats_kernel(
    const float* __restrict__ hs_f, const float* __restrict__ hs_b,
    const float* __restrict__ w_out, const float* __restrict__ b_out,
    float* __restrict__ feats)
{
    const int rs0 = blockIdx.x * 16;
    const int tid = threadIdx.x;
    const int r = tid >> 4, cc = tid & 15;

    __shared__ float Hs[16][513];
    for (int i = tid; i < 16 * 256; i += 256) {
        int rr = i >> 8, k = i & 255;
        Hs[rr][k]       = hs_f[(size_t)(rs0 + rr) * H2N + k];
        Hs[rr][256 + k] = hs_b[(size_t)(SLEN - 1 - (rs0 + rr)) * H2N + k];
    }
    __syncthreads();

    float acc = 0.f;
    const float* wr = w_out + (size_t)cc * 512;
#pragma unroll 8
    for (int k = 0; k < 512; k++) acc += Hs[r][k] * wr[k];
    feats[(size_t)(rs0 + r) * NTAG + cc] = acc + b_out[cc];
}

// ---------------- K4: Viterbi scan + backtrack (single wave, LDS back-ptrs) ----------------
// Backpointers nibble-packed in 64 KB LDS (values 0..15): kills the
// dependent global-load chain in scan + backtrack (was ~0.5-1 ms).
__global__ __launch_bounds__(64) void viterbi_kernel(
    const float* __restrict__ feats, const float* __restrict__ trans,
    float* __restrict__ out)
{
    __shared__ unsigned char back_s[SLEN * 8];   // 65536 B, [t][tag/2] nibbles

    const int lane = threadIdx.x;
    const int nx = lane >> 2, pc = lane & 3;   // next tag, prev-chunk

    float tr[4];
#pragma unroll
    for (int j = 0; j < 4; j++) tr[j] = trans[nx * NTAG + pc * 4 + j];

    // score of tag g lives (replicated) in lanes 4g..4g+3
    float sc = (nx == 0) ? 0.f : NEGV;
    float fe = feats[nx];   // prefetch t=0

    for (int t = 0; t < SLEN; t++) {
        float fe_next = (t < SLEN - 1) ? feats[(size_t)(t + 1) * NTAG + nx] : 0.f;

        float bv; int bi;
#pragma unroll
        for (int j = 0; j < 4; j++) {
            float s = __shfl(sc, 4 * (pc * 4 + j), 64);
            float cand = s + tr[j];
            if (j == 0) { bv = cand; bi = pc * 4; }
            else if (cand > bv) { bv = cand; bi = pc * 4 + j; }
        }
        // combine across the 4 prev-chunks; first-max semantics (tie -> smaller idx)
#pragma unroll
        for (int off = 1; off < 4; off <<= 1) {
            float ov = __shfl_xor(bv, off, 64);
            int   oi = __shfl_xor(bi, off, 64);
            if (ov > bv || (ov == bv && oi < bi)) { bv = ov; bi = oi; }
        }
        // nibble-pack: lane (nx even, pc==0) stores [bi(nx) | bi(nx+1)<<4]
        int bi_part = __shfl(bi, (nx | 1) * 4, 64);
        if (pc == 0 && (nx & 1) == 0)
            back_s[t * 8 + (nx >> 1)] = (unsigned char)((bi & 15) | (bi_part << 4));
        sc = bv + fe;
        fe = fe_next;
    }

    // final = last + trans[END=1]; first-argmax
    float bestv = 0.f; int besti = 0;
#pragma unroll
    for (int j = 0; j < NTAG; j++) {
        float sj = __shfl(sc, 4 * j, 64);
        float fj = sj + trans[1 * NTAG + j];
        if (j == 0) { bestv = fj; besti = 0; }
        else if (fj > bestv) { bestv = fj; besti = j; }
    }
    __syncthreads();

    if (lane == 0) {
        out[0] = bestv;
        int cur = besti;
        for (int t = SLEN - 1; t >= 1; t--) {
            out[1 + t] = (float)cur;
            unsigned char byte = back_s[t * 8 + (cur >> 1)];
            cur = (cur & 1) ? (byte >> 4) : (byte & 15);
        }
        out[1] = (float)cur;
    }
}

extern "C" void kernel_launch(void* const* d_in, const int* in_sizes, int n_in,
                              void* d_out, int out_size, void* d_ws, size_t ws_size,
                              hipStream_t stream) {
    const int*   sent   = (const int*)d_in[0];
    const float* emb    = (const float*)d_in[1];
    const float* w_ih_f = (const float*)d_in[2];
    const float* w_hh_f = (const float*)d_in[3];
    const float* b_f    = (const float*)d_in[4];
    const float* w_ih_b = (const float*)d_in[5];
    const float* w_hh_b = (const float*)d_in[6];
    const float* b_b    = (const float*)d_in[7];
    const float* h0_f   = (const float*)d_in[8];
    const float* c0_f   = (const float*)d_in[9];
    const float* h0_b   = (const float*)d_in[10];
    const float* c0_b   = (const float*)d_in[11];
    const float* w_out  = (const float*)d_in[12];
    const float* b_out  = (const float*)d_in[13];
    const float* trans  = (const float*)d_in[14];
    float* out = (float*)d_out;

    if (ws_size < WS_NEEDED) return;  // visible failure, no OOB writes

    float* ws = (float*)d_ws;
    float* pre_f = ws + OFF_PRE_F;
    float* pre_b = ws + OFF_PRE_B;
    float* hs_f  = ws + OFF_HS_F;
    float* hs_b  = ws + OFF_HS_B;
    float* feats = ws + OFF_FEATS;

    gemm_pre<<<dim3(128, 16, 2), 256, 0, stream>>>(sent, emb, w_ih_f, b_f, w_ih_b, b_b, pre_f, pre_b);
    lstm_kernel<<<64, 64, 0, stream>>>(pre_f, pre_b, w_hh_f, w_hh_b,
                                       h0_f, c0_f, h0_b, c0_b, hs_f, hs_b);
    feats_kernel<<<512, 256, 0, stream>>>(hs_f, hs_b, w_out, b_out, feats);
    viterbi_kernel<<<1, 64, 0, stream>>>(feats, trans, out);
}

// Round 6
// 21741.884 us; speedup vs baseline: 1.1290x; 1.1290x over previous
//
#include <hip/hip_runtime.h>
#include <math.h>

#define SLEN 8192
#define DIM  256
#define H2N  256
#define G4   1024
#define NTAG 16
#define NEGV (-10000.0f)

// ws layout (floats unless noted)
#define OFF_PRE_F   0
#define OFF_PRE_B   (SLEN*G4)
#define OFF_HS_F    (2*SLEN*G4)
#define OFF_HS_B    (2*SLEN*G4 + SLEN*H2N)
#define OFF_FEATS   (2*SLEN*G4 + 2*SLEN*H2N)
#define WS_NEEDED   ((size_t)(OFF_FEATS + SLEN*NTAG) * 4)

// ---------------- K1: pre = gather(emb, sentence[±]) @ w_ih^T + b ----------------
__global__ __launch_bounds__(256) void gemm_pre(
    const int* __restrict__ sent, const float* __restrict__ emb,
    const float* __restrict__ wf, const float* __restrict__ bf,
    const float* __restrict__ wb, const float* __restrict__ bb,
    float* __restrict__ pre_f, float* __restrict__ pre_b)
{
    const int dir = blockIdx.z;
    const float* w    = dir ? wb : wf;
    const float* bias = dir ? bb : bf;
    float* out        = dir ? pre_b : pre_f;
    const int m0 = blockIdx.x * 64, n0 = blockIdx.y * 64;

    __shared__ float As[64][17];
    __shared__ float Bs[64][17];
    __shared__ int   sidx[64];

    const int tid = threadIdx.x;
    const int tx = tid & 15, ty = tid >> 4;

    if (tid < 64) {
        int m = m0 + tid;
        int pos = dir ? (SLEN - 1 - m) : m;
        sidx[tid] = sent[pos];
    }
    __syncthreads();

    float acc[4][4];
#pragma unroll
    for (int i = 0; i < 4; i++)
#pragma unroll
        for (int j = 0; j < 4; j++) acc[i][j] = 0.f;

    const int lr = tid >> 2, lc = (tid & 3) * 4;

    for (int k0 = 0; k0 < DIM; k0 += 16) {
        float4 av = *(const float4*)(emb + (size_t)sidx[lr] * DIM + k0 + lc);
        float4 bv = *(const float4*)(w + (size_t)(n0 + lr) * DIM + k0 + lc);
        As[lr][lc+0] = av.x; As[lr][lc+1] = av.y; As[lr][lc+2] = av.z; As[lr][lc+3] = av.w;
        Bs[lr][lc+0] = bv.x; Bs[lr][lc+1] = bv.y; Bs[lr][lc+2] = bv.z; Bs[lr][lc+3] = bv.w;
        __syncthreads();
#pragma unroll
        for (int k = 0; k < 16; k++) {
            float a[4], b[4];
#pragma unroll
            for (int i = 0; i < 4; i++) a[i] = As[ty*4+i][k];
#pragma unroll
            for (int j = 0; j < 4; j++) b[j] = Bs[tx*4+j][k];
#pragma unroll
            for (int i = 0; i < 4; i++)
#pragma unroll
                for (int j = 0; j < 4; j++) acc[i][j] += a[i] * b[j];
        }
        __syncthreads();
    }

    float4 b4 = *(const float4*)(bias + n0 + tx*4);
#pragma unroll
    for (int i = 0; i < 4; i++) {
        float4 v;
        v.x = acc[i][0] + b4.x; v.y = acc[i][1] + b4.y;
        v.z = acc[i][2] + b4.z; v.w = acc[i][3] + b4.w;
        *(float4*)(out + (size_t)(m0 + ty*4 + i) * G4 + n0 + tx*4) = v;
    }
}

__device__ __forceinline__ float fast_sigmoid(float x) {
    return 1.f / (1.f + __expf(-x));
}
__device__ __forceinline__ float fast_tanh(float x) {
    float xc = fminf(fmaxf(x, -15.f), 15.f);
    float e = __expf(2.f * xc);
    return (e - 1.f) / (e + 1.f);
}

// ---------------- K2: two LSTMs, 32 blocks/direction ----------------
// R5 lesson: serialized per-dword polls cost ~2.4 ms (4 dependent RTs vs 1)
// -> reverted to R4 parallel-4-load spin.
// W residency attempt #3: stage W in LDS (packed, conflict-free), then each
// thread copies its 128 f32 into VGPRs through a per-float asm "+v" barrier.
// If the allocator spills/remats, it remats *LDS* reads (= R4 behavior,
// neutral); if it sticks (VGPR_Count >= ~200), dot issue drops ~400 cy/step.
// Sync unchanged: data-as-flag (mantissa bit0=1, <=1 ulp), agent-scope
// relaxed store/load, monotone fresh addresses (poison 0xAA has bit0=0).
__global__ __launch_bounds__(64)
__attribute__((amdgpu_waves_per_eu(1, 1)))
void lstm_kernel(
    const float* __restrict__ pre_f, const float* __restrict__ pre_b,
    const float* __restrict__ whh_f, const float* __restrict__ whh_b,
    const float* __restrict__ h0_f, const float* __restrict__ c0_f,
    const float* __restrict__ h0_b, const float* __restrict__ c0_b,
    float* __restrict__ hs_f, float* __restrict__ hs_b)
{
    const int blk = blockIdx.x;            // 0..63
    const int d = blk >> 5, cb = blk & 31; // direction, cell-block
    const int cell0 = cb * 8;
    const float* pre = d ? pre_b : pre_f;
    const float* whh = d ? whh_b : whh_f;
    const float* h0  = d ? h0_b : h0_f;
    const float* c0  = d ? c0_b : c0_f;
    float* hs        = d ? hs_b : hs_f;

    const int l = threadIdx.x;       // 0..63
    const int r = l >> 1;            // local row 0..31 (gate-major)
    const int half = l & 1;          // k-half: [half*128, half*128+128)
    const int g = r >> 3, cl = r & 7;
    const int grow = g * 256 + cell0 + cl;   // global gate row (0..1023)

    __shared__ __align__(16) float4 w_pack4[32 * 64];   // 32 KB, [j][lane]
    __shared__ __align__(16) float  h_lds[256];

    // stage W into packed LDS (coalesced global reads, conflict-free writes)
    {
        const float4* src = (const float4*)(whh + (size_t)grow * H2N + half * 128);
#pragma unroll
        for (int j = 0; j < 32; j++) w_pack4[j * 64 + l] = src[j];
    }
    ((float4*)h_lds)[l] = ((const float4*)h0)[l];
    float c = (l < 8) ? c0[cell0 + l] : 0.f;
    __syncthreads();

    // copy this lane's 128 weights LDS -> VGPRs, pin with asm barrier
    float4 wreg[32];
#pragma unroll
    for (int j = 0; j < 32; j++) wreg[j] = w_pack4[j * 64 + l];
#pragma unroll
    for (int j = 0; j < 32; j++) {
        asm volatile("" : "+v"(wreg[j].x), "+v"(wreg[j].y),
                          "+v"(wreg[j].z), "+v"(wreg[j].w));
    }

    const float* pre_base = pre + grow;
    float pre_cur = (half == 0) ? pre_base[0] : 0.f;
    const int ai = l & 7;            // activation cell index (lanes 0..7)

    for (int t = 0; t < SLEN; t++) {
        float pre_next = (half == 0 && t < SLEN - 1) ? pre_base[(size_t)(t + 1) * G4] : 0.f;

        // dot over this thread's k-half: w from VGPRs, h broadcast from LDS
        float a0 = pre_cur, a1 = 0.f, a2 = 0.f, a3 = 0.f;
        const float4* hrow4 = (const float4*)(h_lds + half * 128);
#pragma unroll
        for (int j = 0; j < 32; j++) {
            float4 wv = wreg[j];
            float4 hv = hrow4[j];
            a0 += wv.x * hv.x; a1 += wv.y * hv.y;
            a2 += wv.z * hv.z; a3 += wv.w * hv.w;
        }
        float sum = (a0 + a1) + (a2 + a3);
        sum += __shfl_xor(sum, 1, 64);   // row r total at lanes 2r, 2r+1

        // gate sums for cell ai: rows ai, 8+ai, 16+ai, 24+ai (independent shfls)
        float s_i = __shfl(sum, 2 * ai, 64);
        float s_f = __shfl(sum, 16 + 2 * ai, 64);
        float s_g = __shfl(sum, 32 + 2 * ai, 64);
        float s_o = __shfl(sum, 48 + 2 * ai, 64);

        if (l < 8) {
            float i_ = fast_sigmoid(s_i);
            float f_ = fast_sigmoid(s_f);
            float g_ = fast_tanh(s_g);
            float o_ = fast_sigmoid(s_o);
            c = f_ * c + i_ * g_;
            float h = o_ * fast_tanh(c);
            unsigned hm = __float_as_uint(h) | 1u;   // flag bit, <=1 ulp
            __hip_atomic_store((unsigned*)hs + (size_t)t * H2N + cell0 + l, hm,
                               __ATOMIC_RELAXED, __HIP_MEMORY_SCOPE_AGENT);
        }

        // every lane pulls 4 cells; 4 PARALLEL loads per spin round (R4 style:
        // detection granularity = 1 round trip, not 4)
        const unsigned* hsrc = (const unsigned*)hs + (size_t)t * H2N + 4 * l;
        unsigned v0, v1, v2, v3;
        int spin = 0;
        do {
            v0 = __hip_atomic_load(hsrc + 0, __ATOMIC_RELAXED, __HIP_MEMORY_SCOPE_AGENT);
            v1 = __hip_atomic_load(hsrc + 1, __ATOMIC_RELAXED, __HIP_MEMORY_SCOPE_AGENT);
            v2 = __hip_atomic_load(hsrc + 2, __ATOMIC_RELAXED, __HIP_MEMORY_SCOPE_AGENT);
            v3 = __hip_atomic_load(hsrc + 3, __ATOMIC_RELAXED, __HIP_MEMORY_SCOPE_AGENT);
        } while (((v0 & v1 & v2 & v3 & 1u) == 0u) && ++spin < 2000000);

        float4 hv4;
        hv4.x = __uint_as_float(v0); hv4.y = __uint_as_float(v1);
        hv4.z = __uint_as_float(v2); hv4.w = __uint_as_float(v3);
        *(float4*)(h_lds + 4 * l) = hv4;
        __syncthreads();             // single wave: lgkm drain + barrier
        pre_cur = pre_next;
    }
}

// ---------------- K3: feats = concat(hs_f[s], hs_b[S-1-s]) @ w_out^T + b_out ----------------
__global__ __launch_bounds__(256) void feats_kernel(
    const float* __restrict__ hs_f, const float* __restrict__ hs_b,
    const float* __restrict__ w_out, const float* __restrict__ b_out,
    float* __restrict__ feats)
{
    const int rs0 = blockIdx.x * 16;
    const int tid = threadIdx.x;
    const int r = tid >> 4, cc = tid & 15;

    __shared__ float Hs[16][513];
    for (int i = tid; i < 16 * 256; i += 256) {
        int rr = i >> 8, k = i & 255;
        Hs[rr][k]       = hs_f[(size_t)(rs0 + rr) * H2N + k];
        Hs[rr][256 + k] = hs_b[(size_t)(SLEN - 1 - (rs0 + rr)) * H2N + k];
    }
    __syncthreads();

    float acc = 0.f;
    const float* wr = w_out + (size_t)cc * 512;
#pragma unroll 8
    for (int k = 0; k < 512; k++) acc += Hs[r][k] * wr[k];
    feats[(size_t)(rs0 + r) * NTAG + cc] = acc + b_out[cc];
}

// ---------------- K4: Viterbi scan + backtrack (single wave, LDS back-ptrs) ----------------
__global__ __launch_bounds__(64) void viterbi_kernel(
    const float* __restrict__ feats, const float* __restrict__ trans,
    float* __restrict__ out)
{
    __shared__ unsigned char back_s[SLEN * 8];   // 65536 B, [t][tag/2] nibbles

    const int lane = threadIdx.x;
    const int nx = lane >> 2, pc = lane & 3;   // next tag, prev-chunk

    float tr[4];
#pragma unroll
    for (int j = 0; j < 4; j++) tr[j] = trans[nx * NTAG + pc * 4 + j];

    // score of tag g lives (replicated) in lanes 4g..4g+3
    float sc = (nx == 0) ? 0.f : NEGV;
    float fe = feats[nx];   // prefetch t=0

    for (int t = 0; t < SLEN; t++) {
        float fe_next = (t < SLEN - 1) ? feats[(size_t)(t + 1) * NTAG + nx] : 0.f;

        float bv; int bi;
#pragma unroll
        for (int j = 0; j < 4; j++) {
            float s = __shfl(sc, 4 * (pc * 4 + j), 64);
            float cand = s + tr[j];
            if (j == 0) { bv = cand; bi = pc * 4; }
            else if (cand > bv) { bv = cand; bi = pc * 4 + j; }
        }
        // combine across the 4 prev-chunks; first-max semantics (tie -> smaller idx)
#pragma unroll
        for (int off = 1; off < 4; off <<= 1) {
            float ov = __shfl_xor(bv, off, 64);
            int   oi = __shfl_xor(bi, off, 64);
            if (ov > bv || (ov == bv && oi < bi)) { bv = ov; bi = oi; }
        }
        // nibble-pack: lane (nx even, pc==0) stores [bi(nx) | bi(nx+1)<<4]
        int bi_part = __shfl(bi, (nx | 1) * 4, 64);
        if (pc == 0 && (nx & 1) == 0)
            back_s[t * 8 + (nx >> 1)] = (unsigned char)((bi & 15) | (bi_part << 4));
        sc = bv + fe;
        fe = fe_next;
    }

    // final = last + trans[END=1]; first-argmax
    float bestv = 0.f; int besti = 0;
#pragma unroll
    for (int j = 0; j < NTAG; j++) {
        float sj = __shfl(sc, 4 * j, 64);
        float fj = sj + trans[1 * NTAG + j];
        if (j == 0) { bestv = fj; besti = 0; }
        else if (fj > bestv) { bestv = fj; besti = j; }
    }
    __syncthreads();

    if (lane == 0) {
        out[0] = bestv;
        int cur = besti;
        for (int t = SLEN - 1; t >= 1; t--) {
            out[1 + t] = (float)cur;
            unsigned char byte = back_s[t * 8 + (cur >> 1)];
            cur = (cur & 1) ? (byte >> 4) : (byte & 15);
        }
        out[1] = (float)cur;
    }
}

extern "C" void kernel_launch(void* const* d_in, const int* in_sizes, int n_in,
                              void* d_out, int out_size, void* d_ws, size_t ws_size,
                              hipStream_t stream) {
    const int*   sent   = (const int*)d_in[0];
    const float* emb    = (const float*)d_in[1];
    const float* w_ih_f = (const float*)d_in[2];
    const float* w_hh_f = (const float*)d_in[3];
    const float* b_f    = (const float*)d_in[4];
    const float* w_ih_b = (const float*)d_in[5];
    const float* w_hh_b = (const float*)d_in[6];
    const float* b_b    = (const float*)d_in[7];
    const float* h0_f   = (const float*)d_in[8];
    const float* c0_f   = (const float*)d_in[9];
    const float* h0_b   = (const float*)d_in[10];
    const float* c0_b   = (const float*)d_in[11];
    const float* w_out  = (const float*)d_in[12];
    const float* b_out  = (const float*)d_in[13];
    const float* trans  = (const float*)d_in[14];
    float* out = (float*)d_out;

    if (ws_size < WS_NEEDED) return;  // visible failure, no OOB writes

    float* ws = (float*)d_ws;
    float* pre_f = ws + OFF_PRE_F;
    float* pre_b = ws + OFF_PRE_B;
    float* hs_f  = ws + OFF_HS_F;
    float* hs_b  = ws + OFF_HS_B;
    float* feats = ws + OFF_FEATS;

    gemm_pre<<<dim3(128, 16, 2), 256, 0, stream>>>(sent, emb, w_ih_f, b_f, w_ih_b, b_b, pre_f, pre_b);
    lstm_kernel<<<64, 64, 0, stream>>>(pre_f, pre_b, w_hh_f, w_hh_b,
                                       h0_f, c0_f, h0_b, c0_b, hs_f, hs_b);
    feats_kernel<<<512, 256, 0, stream>>>(hs_f, hs_b, w_out, b_out, feats);
    viterbi_kernel<<<1, 64, 0, stream>>>(feats, trans, out);
}

// Round 7
// 21190.749 us; speedup vs baseline: 1.1584x; 1.0260x over previous
//
#include <hip/hip_runtime.h>
#include <math.h>

#define SLEN 8192
#define DIM  256
#define H2N  256
#define G4   1024
#define NTAG 16
#define NEGV (-10000.0f)

// ws layout (float offsets unless noted)
#define OFF_PRE_F   0
#define OFF_PRE_B   (SLEN*G4)
#define OFF_HS_F    (2*SLEN*G4)
#define OFF_HS_B    (2*SLEN*G4 + SLEN*H2N)
#define OFF_FEATS   (2*SLEN*G4 + 2*SLEN*H2N)
#define OFF_MBOX    (OFF_FEATS + SLEN*NTAG)      // 2 dir x 2 buf x 256
#define WS_NEEDED   ((size_t)(OFF_MBOX + 1024) * 4)

// ---------------- K1: pre = gather(emb, sentence[±]) @ w_ih^T + b ----------------
// R7: LDS staged TRANSPOSED ([k][m]) so the inner loop is 2 ds_read_b128 +
// 16 FMA per k (was 128 scalar LDS column reads per k0-tile). Same
// accumulation order as before -> bit-identical output.
__global__ __launch_bounds__(256) void gemm_pre(
    const int* __restrict__ sent, const float* __restrict__ emb,
    const float* __restrict__ wf, const float* __restrict__ bf,
    const float* __restrict__ wb, const float* __restrict__ bb,
    float* __restrict__ pre_f, float* __restrict__ pre_b)
{
    const int dir = blockIdx.z;
    const float* w    = dir ? wb : wf;
    const float* bias = dir ? bb : bf;
    float* out        = dir ? pre_b : pre_f;
    const int m0 = blockIdx.x * 64, n0 = blockIdx.y * 64;

    __shared__ float As[16][68];   // [k][m], row stride 272 B (16B-aligned)
    __shared__ float Bs[16][68];   // [k][n]
    __shared__ int   sidx[64];

    const int tid = threadIdx.x;
    const int tx = tid & 15, ty = tid >> 4;

    if (tid < 64) {
        int m = m0 + tid;
        int pos = dir ? (SLEN - 1 - m) : m;
        sidx[tid] = sent[pos];
    }
    __syncthreads();

    float acc[4][4];
#pragma unroll
    for (int i = 0; i < 4; i++)
#pragma unroll
        for (int j = 0; j < 4; j++) acc[i][j] = 0.f;

    const int lr = tid >> 2, lc = (tid & 3) * 4;

    for (int k0 = 0; k0 < DIM; k0 += 16) {
        float4 av = *(const float4*)(emb + (size_t)sidx[lr] * DIM + k0 + lc);
        float4 bv = *(const float4*)(w + (size_t)(n0 + lr) * DIM + k0 + lc);
        As[lc+0][lr] = av.x; As[lc+1][lr] = av.y; As[lc+2][lr] = av.z; As[lc+3][lr] = av.w;
        Bs[lc+0][lr] = bv.x; Bs[lc+1][lr] = bv.y; Bs[lc+2][lr] = bv.z; Bs[lc+3][lr] = bv.w;
        __syncthreads();
#pragma unroll
        for (int k = 0; k < 16; k++) {
            float4 a4 = *(const float4*)&As[k][ty * 4];
            float4 b4 = *(const float4*)&Bs[k][tx * 4];
            float a[4] = {a4.x, a4.y, a4.z, a4.w};
            float b[4] = {b4.x, b4.y, b4.z, b4.w};
#pragma unroll
            for (int i = 0; i < 4; i++)
#pragma unroll
                for (int j = 0; j < 4; j++) acc[i][j] += a[i] * b[j];
        }
        __syncthreads();
    }

    float4 b4 = *(const float4*)(bias + n0 + tx*4);
#pragma unroll
    for (int i = 0; i < 4; i++) {
        float4 v;
        v.x = acc[i][0] + b4.x; v.y = acc[i][1] + b4.y;
        v.z = acc[i][2] + b4.z; v.w = acc[i][3] + b4.w;
        *(float4*)(out + (size_t)(m0 + ty*4 + i) * G4 + n0 + tx*4) = v;
    }
}

__device__ __forceinline__ float fast_sigmoid(float x) {
    return 1.f / (1.f + __expf(-x));
}
__device__ __forceinline__ float fast_tanh(float x) {
    float xc = fminf(fmaxf(x, -15.f), 15.f);
    float e = __expf(2.f * xc);
    return (e - 1.f) / (e + 1.f);
}

// ---------------- K2: two LSTMs, 32 blocks/direction, hot-mailbox sync ----------------
// R6 analysis: exchange ~4,000 of 5,500 cy/step because each step's h lives
// at a FRESH 1 KB address -> every poll is a cold LLC/HBM miss (FETCH 287MB).
// R7: exchange via fixed 2-buffer mailbox (ping-pong on t&1) so the lines
// stay LLC-resident. ABA safety: max producer/consumer skew is 1 step
// (reaching t+1 requires having observed all h_t), so a 1-bit tag
// distinguishing t from t-2 suffices: mantissa bit0 = ((t>>1)&1)^1.
// Poison 0xAA has bit0=0 != expected tag 1 at t=0/1 -> no false positive.
// h history for feats is written separately with nontemporal stores
// (off the critical path; consumers never read it).
__global__ __launch_bounds__(64) void lstm_kernel(
    const float* __restrict__ pre_f, const float* __restrict__ pre_b,
    const float* __restrict__ whh_f, const float* __restrict__ whh_b,
    const float* __restrict__ h0_f, const float* __restrict__ c0_f,
    const float* __restrict__ h0_b, const float* __restrict__ c0_b,
    float* __restrict__ hs_f, float* __restrict__ hs_b,
    unsigned* __restrict__ mbox)
{
    const int blk = blockIdx.x;            // 0..63
    const int d = blk >> 5, cb = blk & 31; // direction, cell-block
    const int cell0 = cb * 8;
    const float* pre = d ? pre_b : pre_f;
    const float* whh = d ? whh_b : whh_f;
    const float* h0  = d ? h0_b : h0_f;
    const float* c0  = d ? c0_b : c0_f;
    float* hs        = d ? hs_b : hs_f;

    const int l = threadIdx.x;       // 0..63
    const int r = l >> 1;            // local row 0..31 (gate-major)
    const int half = l & 1;          // k-half: [half*128, half*128+128)
    const int g = r >> 3, cl = r & 7;
    const int grow = g * 256 + cell0 + cl;   // global gate row (0..1023)

    __shared__ __align__(16) float4 w_pack4[32 * 64];   // 32 KB, [j][lane]
    __shared__ __align__(16) float  h_lds[256];

    // stage W into packed LDS (coalesced global reads, conflict-free reads)
    {
        const float4* src = (const float4*)(whh + (size_t)grow * H2N + half * 128);
#pragma unroll
        for (int j = 0; j < 32; j++) w_pack4[j * 64 + l] = src[j];
    }
    ((float4*)h_lds)[l] = ((const float4*)h0)[l];
    float c = (l < 8) ? c0[cell0 + l] : 0.f;
    __syncthreads();

    const float* pre_base = pre + grow;
    float pre_cur = (half == 0) ? pre_base[0] : 0.f;
    const int ai = l & 7;            // activation cell index (lanes 0..7)
    unsigned* mb_dir = mbox + d * 512;

    for (int t = 0; t < SLEN; t++) {
        float pre_next = (half == 0 && t < SLEN - 1) ? pre_base[(size_t)(t + 1) * G4] : 0.f;
        const unsigned etag = (((unsigned)t >> 1) & 1u) ^ 1u;
        unsigned* mb = mb_dir + (t & 1) * 256;

        // dot over this thread's k-half: w + h from LDS (conflict-free)
        float a0 = pre_cur, a1 = 0.f, a2 = 0.f, a3 = 0.f;
        const float4* hrow4 = (const float4*)(h_lds + half * 128);
#pragma unroll
        for (int j = 0; j < 32; j++) {
            float4 wv = w_pack4[j * 64 + l];
            float4 hv = hrow4[j];
            a0 += wv.x * hv.x; a1 += wv.y * hv.y;
            a2 += wv.z * hv.z; a3 += wv.w * hv.w;
        }
        float sum = (a0 + a1) + (a2 + a3);
        sum += __shfl_xor(sum, 1, 64);   // row r total at lanes 2r, 2r+1

        // gate sums for cell ai: rows ai, 8+ai, 16+ai, 24+ai
        float s_i = __shfl(sum, 2 * ai, 64);
        float s_f = __shfl(sum, 16 + 2 * ai, 64);
        float s_g = __shfl(sum, 32 + 2 * ai, 64);
        float s_o = __shfl(sum, 48 + 2 * ai, 64);

        if (l < 8) {
            float i_ = fast_sigmoid(s_i);
            float f_ = fast_sigmoid(s_f);
            float g_ = fast_tanh(s_g);
            float o_ = fast_sigmoid(s_o);
            c = f_ * c + i_ * g_;
            float h = o_ * fast_tanh(c);
            unsigned hm = (__float_as_uint(h) & ~1u) | etag;   // tag bit, <=1 ulp
            __hip_atomic_store(mb + cell0 + l, hm,
                               __ATOMIC_RELAXED, __HIP_MEMORY_SCOPE_AGENT);
            // history for feats: off critical path, nontemporal
            __builtin_nontemporal_store(hm, (unsigned*)hs + (size_t)t * H2N + cell0 + l);
        }

        // every lane pulls 4 cells from the hot mailbox; 4 parallel loads
        // per spin round (detection granularity = 1 round trip)
        const unsigned* msrc = mb + 4 * l;
        unsigned v0, v1, v2, v3;
        int spin = 0;
        do {
            v0 = __hip_atomic_load(msrc + 0, __ATOMIC_RELAXED, __HIP_MEMORY_SCOPE_AGENT);
            v1 = __hip_atomic_load(msrc + 1, __ATOMIC_RELAXED, __HIP_MEMORY_SCOPE_AGENT);
            v2 = __hip_atomic_load(msrc + 2, __ATOMIC_RELAXED, __HIP_MEMORY_SCOPE_AGENT);
            v3 = __hip_atomic_load(msrc + 3, __ATOMIC_RELAXED, __HIP_MEMORY_SCOPE_AGENT);
        } while ((((v0 ^ etag) | (v1 ^ etag) | (v2 ^ etag) | (v3 ^ etag)) & 1u)
                 && ++spin < 2000000);

        float4 hv4;
        hv4.x = __uint_as_float(v0); hv4.y = __uint_as_float(v1);
        hv4.z = __uint_as_float(v2); hv4.w = __uint_as_float(v3);
        *(float4*)(h_lds + 4 * l) = hv4;
        __syncthreads();             // single wave: lgkm drain + barrier
        pre_cur = pre_next;
    }
}

// ---------------- K3: feats = concat(hs_f[s], hs_b[S-1-s]) @ w_out^T + b_out ----------------
__global__ __launch_bounds__(256) void feats_kernel(
    const float* __restrict__ hs_f, const float* __restrict__ hs_b,
    const float* __restrict__ w_out, const float* __restrict__ b_out,
    float* __restrict__ feats)
{
    const int rs0 = blockIdx.x * 16;
    const int tid = threadIdx.x;
    const int r = tid >> 4, cc = tid & 15;

    __shared__ float Hs[16][516];   // row stride 2064 B (16B-aligned)
    for (int i = tid; i < 16 * 256; i += 256) {
        int rr = i >> 8, k = i & 255;
        Hs[rr][k]       = hs_f[(size_t)(rs0 + rr) * H2N + k];
        Hs[rr][256 + k] = hs_b[(size_t)(SLEN - 1 - (rs0 + rr)) * H2N + k];
    }
    __syncthreads();

    float acc = 0.f;
    const float* wr = w_out + (size_t)cc * 512;
    const float* hrow = Hs[r];
#pragma unroll 4
    for (int kq = 0; kq < 128; kq++) {
        float4 hv = *(const float4*)(hrow + 4 * kq);
        float4 wv = *(const float4*)(wr + 4 * kq);
        acc += hv.x * wv.x; acc += hv.y * wv.y;
        acc += hv.z * wv.z; acc += hv.w * wv.w;
    }
    feats[(size_t)(rs0 + r) * NTAG + cc] = acc + b_out[cc];
}

// ---------------- K4: Viterbi scan + backtrack (single wave, LDS back-ptrs) ----------------
__global__ __launch_bounds__(64) void viterbi_kernel(
    const float* __restrict__ feats, const float* __restrict__ trans,
    float* __restrict__ out)
{
    __shared__ unsigned char back_s[SLEN * 8];   // 65536 B, [t][tag/2] nibbles

    const int lane = threadIdx.x;
    const int nx = lane >> 2, pc = lane & 3;   // next tag, prev-chunk

    float tr[4];
#pragma unroll
    for (int j = 0; j < 4; j++) tr[j] = trans[nx * NTAG + pc * 4 + j];

    // score of tag g lives (replicated) in lanes 4g..4g+3
    float sc = (nx == 0) ? 0.f : NEGV;
    float fe = feats[nx];   // prefetch t=0

    for (int t = 0; t < SLEN; t++) {
        float fe_next = (t < SLEN - 1) ? feats[(size_t)(t + 1) * NTAG + nx] : 0.f;

        float bv; int bi;
#pragma unroll
        for (int j = 0; j < 4; j++) {
            float s = __shfl(sc, 4 * (pc * 4 + j), 64);
            float cand = s + tr[j];
            if (j == 0) { bv = cand; bi = pc * 4; }
            else if (cand > bv) { bv = cand; bi = pc * 4 + j; }
        }
        // combine across the 4 prev-chunks; first-max semantics (tie -> smaller idx)
#pragma unroll
        for (int off = 1; off < 4; off <<= 1) {
            float ov = __shfl_xor(bv, off, 64);
            int   oi = __shfl_xor(bi, off, 64);
            if (ov > bv || (ov == bv && oi < bi)) { bv = ov; bi = oi; }
        }
        // nibble-pack: lane (nx even, pc==0) stores [bi(nx) | bi(nx+1)<<4]
        int bi_part = __shfl(bi, (nx | 1) * 4, 64);
        if (pc == 0 && (nx & 1) == 0)
            back_s[t * 8 + (nx >> 1)] = (unsigned char)((bi & 15) | (bi_part << 4));
        sc = bv + fe;
        fe = fe_next;
    }

    // final = last + trans[END=1]; first-argmax
    float bestv = 0.f; int besti = 0;
#pragma unroll
    for (int j = 0; j < NTAG; j++) {
        float sj = __shfl(sc, 4 * j, 64);
        float fj = sj + trans[1 * NTAG + j];
        if (j == 0) { bestv = fj; besti = 0; }
        else if (fj > bestv) { bestv = fj; besti = j; }
    }
    __syncthreads();

    if (lane == 0) {
        out[0] = bestv;
        int cur = besti;
        for (int t = SLEN - 1; t >= 1; t--) {
            out[1 + t] = (float)cur;
            unsigned char byte = back_s[t * 8 + (cur >> 1)];
            cur = (cur & 1) ? (byte >> 4) : (byte & 15);
        }
        out[1] = (float)cur;
    }
}

extern "C" void kernel_launch(void* const* d_in, const int* in_sizes, int n_in,
                              void* d_out, int out_size, void* d_ws, size_t ws_size,
                              hipStream_t stream) {
    const int*   sent   = (const int*)d_in[0];
    const float* emb    = (const float*)d_in[1];
    const float* w_ih_f = (const float*)d_in[2];
    const float* w_hh_f = (const float*)d_in[3];
    const float* b_f    = (const float*)d_in[4];
    const float* w_ih_b = (const float*)d_in[5];
    const float* w_hh_b = (const float*)d_in[6];
    const float* b_b    = (const float*)d_in[7];
    const float* h0_f   = (const float*)d_in[8];
    const float* c0_f   = (const float*)d_in[9];
    const float* h0_b   = (const float*)d_in[10];
    const float* c0_b   = (const float*)d_in[11];
    const float* w_out  = (const float*)d_in[12];
    const float* b_out  = (const float*)d_in[13];
    const float* trans  = (const float*)d_in[14];
    float* out = (float*)d_out;

    if (ws_size < WS_NEEDED) return;  // visible failure, no OOB writes

    float* ws = (float*)d_ws;
    float* pre_f = ws + OFF_PRE_F;
    float* pre_b = ws + OFF_PRE_B;
    float* hs_f  = ws + OFF_HS_F;
    float* hs_b  = ws + OFF_HS_B;
    float* feats = ws + OFF_FEATS;
    unsigned* mbox = (unsigned*)(ws + OFF_MBOX);

    gemm_pre<<<dim3(128, 16, 2), 256, 0, stream>>>(sent, emb, w_ih_f, b_f, w_ih_b, b_b, pre_f, pre_b);
    lstm_kernel<<<64, 64, 0, stream>>>(pre_f, pre_b, w_hh_f, w_hh_b,
                                       h0_f, c0_f, h0_b, c0_b, hs_f, hs_b, mbox);
    feats_kernel<<<512, 256, 0, stream>>>(hs_f, hs_b, w_out, b_out, feats);
    viterbi_kernel<<<1, 64, 0, stream>>>(feats, trans, out);
}